// Round 1
// baseline (130.008 us; speedup 1.0000x reference)
//
#include <hip/hip_runtime.h>
#include <hip/hip_bf16.h>
#include <math.h>

// Problem constants (match reference)
#define NSAMP   8192
#define BATCH   16
#define CHW     65536
#define EPS_F   1e-12f

// Pair-kernel tiling
#define THREADS 256
#define TILE_I  128                 // i-rows staged in LDS per block
#define JREG    2                   // j-rows held in registers per thread
#define TILE_J  (THREADS * JREG)    // 512 j-cols per block
#define NTI     (NSAMP / TILE_I)    // 64
#define NTJ     (NSAMP / TILE_J)    // 16
// lower-triangle tile blocks: sum_{bj=0}^{15} (64 - 4*bj) = 544
#define NBLOCKS 544

// ws layout (bytes):
//   [0,        32768)  : partials double[NBLOCKS*5]
//   [32768,   557056)  : Xn  float[8192*16]   (centered+L2-normalized rows)
//   [557056,  622592)  : C2  float[8192*2]    (gathered coords)

// ---------------------------------------------------------------- kernel 1
__global__ void __launch_bounds__(256)
prep_kernel(const float* __restrict__ feat, const float* __restrict__ coords,
            const int* __restrict__ sidx, float* __restrict__ Xn,
            float* __restrict__ C2) {
    int n = blockIdx.x * blockDim.x + threadIdx.x;
    if (n >= NSAMP) return;
    int id = sidx[n];
    float f[BATCH];
    float mean = 0.f;
#pragma unroll
    for (int b = 0; b < BATCH; ++b) { f[b] = feat[b * CHW + id]; mean += f[b]; }
    mean *= (1.f / BATCH);
    float ss = 0.f;
#pragma unroll
    for (int b = 0; b < BATCH; ++b) { f[b] -= mean; ss = fmaf(f[b], f[b], ss); }
    float inv = 1.f / sqrtf(ss);
#pragma unroll
    for (int q = 0; q < 4; ++q) {
        float4 o;
        o.x = f[q * 4 + 0] * inv; o.y = f[q * 4 + 1] * inv;
        o.z = f[q * 4 + 2] * inv; o.w = f[q * 4 + 3] * inv;
        reinterpret_cast<float4*>(Xn)[n * 4 + q] = o;
    }
    float2 c;
    c.x = coords[id * 2 + 0];
    c.y = coords[id * 2 + 1];
    reinterpret_cast<float2*>(C2)[n] = c;
}

// ---------------------------------------------------------------- kernel 2
// 16-element dot of LDS i-row (xi0..xi3) with register j-row xj[4]
#define DOT16(res, xj)                                                        \
    {                                                                         \
        res = xi0.x * xj[0].x;                                                \
        res = fmaf(xi0.y, xj[0].y, res); res = fmaf(xi0.z, xj[0].z, res);     \
        res = fmaf(xi0.w, xj[0].w, res); res = fmaf(xi1.x, xj[1].x, res);     \
        res = fmaf(xi1.y, xj[1].y, res); res = fmaf(xi1.z, xj[1].z, res);     \
        res = fmaf(xi1.w, xj[1].w, res); res = fmaf(xi2.x, xj[2].x, res);     \
        res = fmaf(xi2.y, xj[2].y, res); res = fmaf(xi2.z, xj[2].z, res);     \
        res = fmaf(xi2.w, xj[2].w, res); res = fmaf(xi3.x, xj[3].x, res);     \
        res = fmaf(xi3.y, xj[3].y, res); res = fmaf(xi3.z, xj[3].z, res);     \
        res = fmaf(xi3.w, xj[3].w, res);                                      \
    }

__global__ void __launch_bounds__(THREADS)
pair_kernel(const float* __restrict__ Xn, const float* __restrict__ C2,
            double* __restrict__ partials) {
    // block -> (bj, bi): row bj has tiles bi in [4*bj, 64)
    int t = blockIdx.x;
    int bj = 0, off = 0;
    while (bj < NTJ - 1 && t >= off + (NTI - 4 * bj)) { off += NTI - 4 * bj; ++bj; }
    int bi = 4 * bj + (t - off);
    const int iBase = bi * TILE_I;
    const int jBase = bj * TILE_J;
    const int tid = threadIdx.x;

    __shared__ float sXn[TILE_I * 16];
    __shared__ float sC[TILE_I * 2];

    {   // stage i-tile: 128 rows x 16 floats (+ coords) via float4
        const float4* gX = reinterpret_cast<const float4*>(Xn + iBase * 16);
        float4* sX = reinterpret_cast<float4*>(sXn);
#pragma unroll
        for (int v = tid; v < TILE_I * 4; v += THREADS) sX[v] = gX[v];
        const float4* gC = reinterpret_cast<const float4*>(C2 + iBase * 2);
        float4* sC4 = reinterpret_cast<float4*>(sC);
        if (tid < TILE_I * 2 / 4) sC4[tid] = gC[tid];
    }

    // each thread owns 2 consecutive j-rows in registers
    const int gj0 = jBase + tid * JREG;
    float4 xj0[4], xj1[4];
    {
        const float4* g0 = reinterpret_cast<const float4*>(Xn + gj0 * 16);
#pragma unroll
        for (int q = 0; q < 4; ++q) { xj0[q] = g0[q]; xj1[q] = g0[4 + q]; }
    }
    float2 cj0 = reinterpret_cast<const float2*>(C2)[gj0];
    float2 cj1 = reinterpret_cast<const float2*>(C2)[gj0 + 1];

    __syncthreads();

    double dSa = 0, dSb = 0, dSab = 0, dSaa = 0, dSbb = 0;
    float  fSa = 0, fSb = 0, fSab = 0, fSaa = 0, fSbb = 0;
    const float4* sX4 = reinterpret_cast<const float4*>(sXn);

    for (int ii = 0; ii < TILE_I; ++ii) {
        const int gi = iBase + ii;
        float4 xi0 = sX4[ii * 4 + 0], xi1 = sX4[ii * 4 + 1];
        float4 xi2 = sX4[ii * 4 + 2], xi3 = sX4[ii * 4 + 3];
        float cix = sC[ii * 2 + 0], ciy = sC[ii * 2 + 1];

        // pair 0
        float a0; DOT16(a0, xj0);
        float dx0 = cix - cj0.x, dy0 = ciy - cj0.y;
        float s0 = fmaf(dx0, dx0, dy0 * dy0);
        s0 = (s0 > EPS_F) ? s0 : EPS_F;
        float b0 = __builtin_amdgcn_rcpf(sqrtf(s0) + 1.0f);
        if (gi > gj0) {
            fSa += a0; fSb += b0;
            fSab = fmaf(a0, b0, fSab);
            fSaa = fmaf(a0, a0, fSaa);
            fSbb = fmaf(b0, b0, fSbb);
        }
        // pair 1
        float a1; DOT16(a1, xj1);
        float dx1 = cix - cj1.x, dy1 = ciy - cj1.y;
        float s1 = fmaf(dx1, dx1, dy1 * dy1);
        s1 = (s1 > EPS_F) ? s1 : EPS_F;
        float b1 = __builtin_amdgcn_rcpf(sqrtf(s1) + 1.0f);
        if (gi > gj0 + 1) {
            fSa += a1; fSb += b1;
            fSab = fmaf(a1, b1, fSab);
            fSaa = fmaf(a1, a1, fSaa);
            fSbb = fmaf(b1, b1, fSbb);
        }
        // flush bounded fp32 partials (<=64 terms, |term|<=1) to fp64
        if ((ii & 31) == 31) {
            dSa += fSa; dSb += fSb; dSab += fSab; dSaa += fSaa; dSbb += fSbb;
            fSa = fSb = fSab = fSaa = fSbb = 0.f;
        }
    }

    // block reduction (deterministic, no fp atomics)
    const int lane = tid & 63, wid = tid >> 6;
#pragma unroll
    for (int o = 32; o > 0; o >>= 1) {
        dSa  += __shfl_down(dSa,  o, 64);
        dSb  += __shfl_down(dSb,  o, 64);
        dSab += __shfl_down(dSab, o, 64);
        dSaa += __shfl_down(dSaa, o, 64);
        dSbb += __shfl_down(dSbb, o, 64);
    }
    __shared__ double red[4][5];
    if (lane == 0) {
        red[wid][0] = dSa; red[wid][1] = dSb; red[wid][2] = dSab;
        red[wid][3] = dSaa; red[wid][4] = dSbb;
    }
    __syncthreads();
    if (tid == 0) {
#pragma unroll
        for (int q = 0; q < 5; ++q)
            partials[blockIdx.x * 5 + q] =
                red[0][q] + red[1][q] + red[2][q] + red[3][q];
    }
}

// ---------------------------------------------------------------- kernel 3
__global__ void __launch_bounds__(256)
finish_kernel(const double* __restrict__ partials, float* __restrict__ out) {
    double s0 = 0, s1 = 0, s2 = 0, s3 = 0, s4 = 0;
    for (int b = threadIdx.x; b < NBLOCKS; b += 256) {
        s0 += partials[b * 5 + 0]; s1 += partials[b * 5 + 1];
        s2 += partials[b * 5 + 2]; s3 += partials[b * 5 + 3];
        s4 += partials[b * 5 + 4];
    }
    const int lane = threadIdx.x & 63, wid = threadIdx.x >> 6;
#pragma unroll
    for (int o = 32; o > 0; o >>= 1) {
        s0 += __shfl_down(s0, o, 64); s1 += __shfl_down(s1, o, 64);
        s2 += __shfl_down(s2, o, 64); s3 += __shfl_down(s3, o, 64);
        s4 += __shfl_down(s4, o, 64);
    }
    __shared__ double red[4][5];
    if (lane == 0) {
        red[wid][0] = s0; red[wid][1] = s1; red[wid][2] = s2;
        red[wid][3] = s3; red[wid][4] = s4;
    }
    __syncthreads();
    if (threadIdx.x == 0) {
        double Sa  = red[0][0] + red[1][0] + red[2][0] + red[3][0];
        double Sb  = red[0][1] + red[1][1] + red[2][1] + red[3][1];
        double Sab = red[0][2] + red[1][2] + red[2][2] + red[3][2];
        double Saa = red[0][3] + red[1][3] + red[2][3] + red[3][3];
        double Sbb = red[0][4] + red[1][4] + red[2][4] + red[3][4];
        const double cnt = (double)NSAMP * (double)(NSAMP - 1) * 0.5;
        double am = Sa / cnt, bm = Sb / cnt;
        double cov = Sab - cnt * am * bm;
        double va  = Saa - cnt * am * am;
        double vb  = Sbb - cnt * bm * bm;
        double corr = cov / (sqrt(va) * sqrt(vb));
        out[0] = (float)((1.0 - corr) * 0.5);
    }
}

// ---------------------------------------------------------------- launcher
extern "C" void kernel_launch(void* const* d_in, const int* in_sizes, int n_in,
                              void* d_out, int out_size, void* d_ws, size_t ws_size,
                              hipStream_t stream) {
    const float* feat   = (const float*)d_in[0];   // [16,64,32,32] f32
    const float* coords = (const float*)d_in[1];   // [65536,2] f32
    const int*   sidx   = (const int*)d_in[2];     // [8192] int32 (JAX x64 off)
    float* out = (float*)d_out;

    double* partials = (double*)d_ws;
    float*  Xn = (float*)((char*)d_ws + 32768);
    float*  C2 = (float*)((char*)d_ws + 32768 + NSAMP * 16 * 4);

    prep_kernel<<<NSAMP / 256, 256, 0, stream>>>(feat, coords, sidx, Xn, C2);
    pair_kernel<<<NBLOCKS, THREADS, 0, stream>>>(Xn, C2, partials);
    finish_kernel<<<1, 256, 0, stream>>>(partials, out);
}

// Round 5
// 102.728 us; speedup vs baseline: 1.2656x; 1.2656x over previous
//
#include <hip/hip_runtime.h>
#include <hip/hip_bf16.h>
#include <math.h>

// Problem constants (match reference)
#define NSAMP 8192
#define BATCH 16
#define CHW   65536
#define EPS_F 1e-12f

// Pair-kernel tiling: 128x128 block tiles over the lower triangle.
// 4 waves per block in a 2x2 arrangement; each wave owns a 64x64 region
// = 4x4 MFMA tiles of 16x16. No LDS in hot loop: fragments + coords in regs.
#define BT    128
#define NBT   (NSAMP / BT)            // 64
#define NINT  (NBT * (NBT - 1) / 2)   // 2016 strictly-interior blocks
#define NBLK  (NINT + NBT)            // 2080 partial slots (+64 diagonal)

typedef __attribute__((ext_vector_type(8))) short short8v;  // 8 bf16 = 4 VGPR
typedef __attribute__((ext_vector_type(4))) float f32x4;

// ws layout (bytes):
//   [0, 83200)           : partials double[NBLK*5]
//   [86016, 86016+512K)  : XA bf16[8192][32]  row = [hi0..15 | lo0..15]
//   [610304, +64K)       : C2 float[8192][2]  gathered coords
// total ~676 KB
#define OFF_XA 86016
#define OFF_C2 (OFF_XA + NSAMP * 32 * 2)

// ---------------------------------------------------------------- kernel 1
// One 16-lane group per sample: lane b handles batch b. shfl_xor reductions.
__global__ void __launch_bounds__(256)
prep_kernel(const float* __restrict__ feat, const float* __restrict__ coords,
            const int* __restrict__ sidx,
            __hip_bfloat16* __restrict__ XA, float* __restrict__ C2) {
    int t = blockIdx.x * 256 + threadIdx.x;   // 131072 threads total
    int n = t >> 4, b = t & 15;
    int id = sidx[n];
    float v = feat[b * CHW + id];

    float m = v;
    m += __shfl_xor(m, 1, 16); m += __shfl_xor(m, 2, 16);
    m += __shfl_xor(m, 4, 16); m += __shfl_xor(m, 8, 16);
    float c = v - m * (1.0f / 16.0f);
    float q = c * c;
    q += __shfl_xor(q, 1, 16); q += __shfl_xor(q, 2, 16);
    q += __shfl_xor(q, 4, 16); q += __shfl_xor(q, 8, 16);
    float x = c * (1.0f / sqrtf(q));

    // exact split: x = hi + lo + eps, |eps| <= 2^-16 |x|
    __hip_bfloat16 hi = __float2bfloat16(x);
    float hif = __bfloat162float(hi);
    __hip_bfloat16 lo = __float2bfloat16(x - hif);

    XA[n * 32 + b]      = hi;
    XA[n * 32 + 16 + b] = lo;
    if (b == 0) {
        float2 cc = reinterpret_cast<const float2*>(coords)[id];
        reinterpret_cast<float2*>(C2)[n] = cc;
    }
}

// ---------------------------------------------------------------- kernel 2
// a_ij = x_i . x_j via 2 MFMAs (exact fp32 dot, split-bf16), b + moments VALU.
// mfma_f32_16x16x32_bf16: A row = lane&15, k = (lane>>4)*8+e; B col = lane&15,
// same k.  C/D (m89): col = lane&15, row = (lane>>4)*4 + reg.
// [lo|hi] fragment at k-group kg == [hi|lo] row fragment at k-group kg^2.
template<bool DIAG>
__global__ void __launch_bounds__(256)
pair_kernel(const __hip_bfloat16* __restrict__ XA,
            const float* __restrict__ C2,
            double* __restrict__ partials) {
    int bi, bj, slot;
    if (DIAG) {
        bi = bj = blockIdx.x; slot = NINT + blockIdx.x;
    } else {
        int t = blockIdx.x;   // t = bi*(bi-1)/2 + bj, 0 <= bj < bi
        int e = (int)((1.0f + sqrtf(1.0f + 8.0f * (float)t)) * 0.5f);
        while (e * (e - 1) / 2 > t) --e;
        while ((e + 1) * e / 2 <= t) ++e;
        bi = e; bj = t - e * (e - 1) / 2; slot = t;
    }
    const int tid = threadIdx.x;
    const int wid = tid >> 6, l = tid & 63;
    const int wi = wid >> 1, wj = wid & 1;        // 2x2 wave grid
    const int col = l & 15, kg = l >> 4, rb = kg * 4;

    const int iW = bi * BT + wi * 64;
    const int jW = bj * BT + wj * 64;

    float fSa = 0, fSb = 0, fSab = 0, fSaa = 0, fSbb = 0;

    if (!(DIAG && wj > wi)) {   // strictly-upper wave region of diag block: skip
        const short* XAs = reinterpret_cast<const short*>(XA);

        short8v afr[4];
        float cix[4][4], ciy[4][4];
#pragma unroll
        for (int ti = 0; ti < 4; ++ti) {
            int rowA = iW + ti * 16 + col;
            afr[ti] = *reinterpret_cast<const short8v*>(XAs + rowA * 32 + kg * 8);
            const float4* cp =
                reinterpret_cast<const float4*>(C2 + (iW + ti * 16 + rb) * 2);
            float4 ca = cp[0], cb = cp[1];
            cix[ti][0] = ca.x; ciy[ti][0] = ca.y;
            cix[ti][1] = ca.z; ciy[ti][1] = ca.w;
            cix[ti][2] = cb.x; ciy[ti][2] = cb.y;
            cix[ti][3] = cb.z; ciy[ti][3] = cb.w;
        }
#pragma unroll
        for (int tj = 0; tj < 4; ++tj) {
            int rowB = jW + tj * 16 + col;
            short8v bhl = *reinterpret_cast<const short8v*>(XAs + rowB * 32 + kg * 8);
            short8v blh = *reinterpret_cast<const short8v*>(XAs + rowB * 32 + ((kg ^ 2) * 8));
            int gj = jW + tj * 16 + col;
            float2 cj = reinterpret_cast<const float2*>(C2)[gj];
#pragma unroll
            for (int ti = 0; ti < 4; ++ti) {
                if (DIAG && wi == wj && ti < tj) continue;  // fully-upper tile
                f32x4 acc = {0.f, 0.f, 0.f, 0.f};
                acc = __builtin_amdgcn_mfma_f32_16x16x32_bf16(afr[ti], bhl, acc, 0, 0, 0);
                acc = __builtin_amdgcn_mfma_f32_16x16x32_bf16(afr[ti], blh, acc, 0, 0, 0);
                const int giB = iW + ti * 16 + rb;
#pragma unroll
                for (int r = 0; r < 4; ++r) {
                    float a  = acc[r];
                    float dx = cix[ti][r] - cj.x, dy = ciy[ti][r] - cj.y;
                    float s2 = fmaf(dx, dx, dy * dy);
                    s2 = fmaxf(s2, EPS_F);
                    float bb = __builtin_amdgcn_rcpf(sqrtf(s2) + 1.0f);
                    float am = a;
                    if (DIAG) {
                        bool mk = (giB + r) > gj;   // strict lower triangle
                        bb = mk ? bb : 0.0f;        // zeroed b kills ab, b, b^2
                        am = mk ? a  : 0.0f;        // zeroed a kills a, a^2
                    }
                    fSa += am;
                    fSb += bb;
                    fSab = fmaf(a,  bb, fSab);
                    fSaa = fmaf(am, am, fSaa);
                    fSbb = fmaf(bb, bb, fSbb);
                }
            }
        }
    }

    // deterministic block reduction (fp32 partials are <=64 bounded terms)
    double dSa = fSa, dSb = fSb, dSab = fSab, dSaa = fSaa, dSbb = fSbb;
#pragma unroll
    for (int o = 32; o > 0; o >>= 1) {
        dSa  += __shfl_down(dSa,  o, 64);
        dSb  += __shfl_down(dSb,  o, 64);
        dSab += __shfl_down(dSab, o, 64);
        dSaa += __shfl_down(dSaa, o, 64);
        dSbb += __shfl_down(dSbb, o, 64);
    }
    __shared__ double red[4][5];
    if (l == 0) {
        red[wid][0] = dSa;  red[wid][1] = dSb;  red[wid][2] = dSab;
        red[wid][3] = dSaa; red[wid][4] = dSbb;
    }
    __syncthreads();
    if (tid == 0) {
#pragma unroll
        for (int q = 0; q < 5; ++q)
            partials[slot * 5 + q] =
                red[0][q] + red[1][q] + red[2][q] + red[3][q];
    }
}

// ---------------------------------------------------------------- kernel 3
__global__ void __launch_bounds__(256)
finish_kernel(const double* __restrict__ partials, float* __restrict__ out) {
    double s0 = 0, s1 = 0, s2 = 0, s3 = 0, s4 = 0;
    for (int b = threadIdx.x; b < NBLK; b += 256) {
        s0 += partials[b * 5 + 0]; s1 += partials[b * 5 + 1];
        s2 += partials[b * 5 + 2]; s3 += partials[b * 5 + 3];
        s4 += partials[b * 5 + 4];
    }
    const int lane = threadIdx.x & 63, wid = threadIdx.x >> 6;
#pragma unroll
    for (int o = 32; o > 0; o >>= 1) {
        s0 += __shfl_down(s0, o, 64); s1 += __shfl_down(s1, o, 64);
        s2 += __shfl_down(s2, o, 64); s3 += __shfl_down(s3, o, 64);
        s4 += __shfl_down(s4, o, 64);
    }
    __shared__ double red[4][5];
    if (lane == 0) {
        red[wid][0] = s0; red[wid][1] = s1; red[wid][2] = s2;
        red[wid][3] = s3; red[wid][4] = s4;
    }
    __syncthreads();
    if (threadIdx.x == 0) {
        double Sa  = red[0][0] + red[1][0] + red[2][0] + red[3][0];
        double Sb  = red[0][1] + red[1][1] + red[2][1] + red[3][1];
        double Sab = red[0][2] + red[1][2] + red[2][2] + red[3][2];
        double Saa = red[0][3] + red[1][3] + red[2][3] + red[3][3];
        double Sbb = red[0][4] + red[1][4] + red[2][4] + red[3][4];
        const double cnt = (double)NSAMP * (double)(NSAMP - 1) * 0.5;
        double am = Sa / cnt, bm = Sb / cnt;
        double cov = Sab - cnt * am * bm;
        double va  = Saa - cnt * am * am;
        double vb  = Sbb - cnt * bm * bm;
        double corr = cov / (sqrt(va) * sqrt(vb));
        out[0] = (float)((1.0 - corr) * 0.5);
    }
}

// ---------------------------------------------------------------- launcher
extern "C" void kernel_launch(void* const* d_in, const int* in_sizes, int n_in,
                              void* d_out, int out_size, void* d_ws, size_t ws_size,
                              hipStream_t stream) {
    const float* feat   = (const float*)d_in[0];   // [16,64,32,32] f32
    const float* coords = (const float*)d_in[1];   // [65536,2] f32
    const int*   sidx   = (const int*)d_in[2];     // [8192] int
    float* out = (float*)d_out;

    double* partials = (double*)d_ws;
    __hip_bfloat16* XA = (__hip_bfloat16*)((char*)d_ws + OFF_XA);
    float* C2 = (float*)((char*)d_ws + OFF_C2);

    prep_kernel<<<NSAMP * BATCH / 256, 256, 0, stream>>>(feat, coords, sidx,
                                                         XA, C2);
    pair_kernel<false><<<NINT, 256, 0, stream>>>(XA, C2, partials);
    pair_kernel<true><<<NBT, 256, 0, stream>>>(XA, C2, partials);
    finish_kernel<<<1, 256, 0, stream>>>(partials, out);
}